// Round 3
// baseline (845.965 us; speedup 1.0000x reference)
//
#include <hip/hip_runtime.h>
#include <hip/hip_bf16.h>

#define BB 8
#define SS 512
#define DD 1024
#define HH 16
#define DHH 64
#define FFF 4096
#define MM (BB*SS)        // 4096
#define HD (HH*DHH)       // 1024
#define CD ((HH+1)*DHH)   // 1088
#define QKV_LD 3072

#define NEG_MIN (-3.4028234663852886e38f)
#define FLT_MAX_ (3.402823466e+38f)

typedef __attribute__((ext_vector_type(8)))  __bf16 bf16x8;
typedef __attribute__((ext_vector_type(16))) float  f32x16;

__device__ __forceinline__ unsigned short bf16_rne(float x) {
    unsigned int u = __float_as_uint(x);
    u += 0x7FFFu + ((u >> 16) & 1u);
    return (unsigned short)(u >> 16);
}
__device__ __forceinline__ float bf16f(unsigned short h) {
    return __uint_as_float(((unsigned int)h) << 16);
}
__device__ __forceinline__ void split2(float x, unsigned short& h, unsigned short& l) {
    h = bf16_rne(x);
    l = bf16_rne(x - bf16f(h));
}

// ---------------------------------------------------------------- LayerNorm
__global__ __launch_bounds__(256)
void ln_kernel(const float* __restrict__ x, const float* __restrict__ g,
               const float* __restrict__ bta, float* __restrict__ out)
{
    const int row = blockIdx.x;
    const int tid = threadIdx.x;
    const float* xr = x + (size_t)row * DD;
    float4 xv = *(const float4*)(xr + tid * 4);
    float s  = xv.x + xv.y + xv.z + xv.w;
    float ss = xv.x*xv.x + xv.y*xv.y + xv.z*xv.z + xv.w*xv.w;
    #pragma unroll
    for (int off = 32; off > 0; off >>= 1) {
        s  += __shfl_down(s, off);
        ss += __shfl_down(ss, off);
    }
    __shared__ float red[8];
    const int wid = tid >> 6;
    if ((tid & 63) == 0) { red[wid*2] = s; red[wid*2+1] = ss; }
    __syncthreads();
    s  = red[0] + red[2] + red[4] + red[6];
    ss = red[1] + red[3] + red[5] + red[7];
    const float mu  = s * (1.0f / DD);
    const float var = ss * (1.0f / DD) - mu * mu;
    const float inv = 1.0f / sqrtf(var + 1e-6f);
    float4 gv = *(const float4*)(g + tid*4);
    float4 bv = *(const float4*)(bta + tid*4);
    float4 o;
    o.x = (xv.x - mu) * inv * gv.x + bv.x;
    o.y = (xv.y - mu) * inv * gv.y + bv.y;
    o.z = (xv.z - mu) * inv * gv.z + bv.z;
    o.w = (xv.w - mu) * inv * gv.w + bv.w;
    *(float4*)(out + (size_t)row * DD + tid*4) = o;
}

// ---------------------------------------------------------------- MFMA GEMM
// C[M,N] = epi( A[M,K] (fp32) @ B[K,N] (fp32) + bias ), split-bf16 (3 MFMA).
// 128x128 tile, BK=32, 256 thr = 4 waves (2x2), per-wave 2x2 frags 32x32x16.
// LDS holds tiles PRE-PACKED in MFMA fragment order:
//   elem (row,k) at ushort idx ((ks*4 + row/32)*64 + row%32 + 32*((k%16)/8))*8 + k%8
// so each fragment read is base + lane*16B: linear, bank-conflict-free b128.
template<bool QKV, bool HAS_RES, bool LEAKY>
__global__ __launch_bounds__(256)
void gemm_mfma(const float* __restrict__ A,
               const float* __restrict__ B0, const float* __restrict__ B1,
               const float* __restrict__ B2,
               const float* __restrict__ bias0, const float* __restrict__ bias1,
               const float* __restrict__ bias2,
               const float* __restrict__ res, float* __restrict__ C,
               int K, int lda, int ldb, int ldc)
{
    __shared__ unsigned short Ah[4096];
    __shared__ unsigned short Al[4096];
    __shared__ unsigned short Bh[4096];
    __shared__ unsigned short Bl[4096];

    const int tid = threadIdx.x;
    const int bm  = blockIdx.y;
    int bn = blockIdx.x;

    const float* Bw   = B0;
    const float* bias = bias0;
    float scale = 1.0f;
    if (QKV) {
        const int sel = bn >> 3;          // 0:q 1:k 2:v (each 1024 cols)
        Bw   = (sel == 0) ? B0 : (sel == 1 ? B1 : B2);
        bias = (sel == 0) ? bias0 : (sel == 1 ? bias1 : bias2);
        scale = (sel == 0) ? 0.125f : 1.0f;
        bn &= 7;
    }

    const int wid  = tid >> 6, lane = tid & 63;
    const int wr   = wid >> 1, wc = wid & 1;
    const int lr   = lane & 31, kb = lane >> 5;

    f32x16 acc[2][2];
    #pragma unroll
    for (int i = 0; i < 2; i++)
        #pragma unroll
        for (int j = 0; j < 2; j++)
            #pragma unroll
            for (int r = 0; r < 16; r++) acc[i][j][r] = 0.f;

    const int nn = tid & 127, kh = tid >> 7;   // B-staging ownership

    for (int k0 = 0; k0 < K; k0 += 32) {
        // ---- stage A: 128x32 fp32 -> split bf16, packed layout
        #pragma unroll
        for (int u = 0; u < 4; ++u) {
            const int f   = u * 256 + tid;       // float4 index in tile
            const int row = f >> 3, kq = f & 7;  // k = kq*4 + 0..3
            float4 v = *(const float4*)(A + (size_t)(bm*128 + row) * lda + k0 + kq*4);
            ushort4 h4, l4;
            split2(v.x, h4.x, l4.x); split2(v.y, h4.y, l4.y);
            split2(v.z, h4.z, l4.z); split2(v.w, h4.w, l4.w);
            const int idx = ((((kq>>2)*4 + (row>>5))*64) + (row & 31) + 32*((kq>>1)&1))*8
                          + (kq & 1)*4;
            *(ushort4*)&Ah[idx] = h4;
            *(ushort4*)&Al[idx] = l4;
        }
        // ---- stage B: 32x128 fp32 -> transposed [N][K] split bf16, packed
        {
            const float* bp = Bw + (size_t)(k0 + kh*16) * ldb + bn*128 + nn;
            float v[16];
            #pragma unroll
            for (int j = 0; j < 16; ++j) v[j] = bp[(size_t)j * ldb];
            unsigned int hw[8], lw[8];
            #pragma unroll
            for (int j = 0; j < 8; ++j) {
                unsigned short h0, l0, h1, l1;
                split2(v[2*j],   h0, l0);
                split2(v[2*j+1], h1, l1);
                hw[j] = (unsigned int)h0 | ((unsigned int)h1 << 16);
                lw[j] = (unsigned int)l0 | ((unsigned int)l1 << 16);
            }
            const int base = ((kh*4 + (nn>>5))*64 + (nn & 31)) * 8;  // khalf=0
            *(uint4*)&Bh[base]       = make_uint4(hw[0], hw[1], hw[2], hw[3]);
            *(uint4*)&Bh[base + 256] = make_uint4(hw[4], hw[5], hw[6], hw[7]); // khalf=1
            *(uint4*)&Bl[base]       = make_uint4(lw[0], lw[1], lw[2], lw[3]);
            *(uint4*)&Bl[base + 256] = make_uint4(lw[4], lw[5], lw[6], lw[7]);
        }
        __syncthreads();

        #pragma unroll
        for (int ks = 0; ks < 2; ++ks) {
            bf16x8 ah[2], al2[2], bh2[2], bl2[2];
            #pragma unroll
            for (int mf = 0; mf < 2; ++mf) {
                const int idx = ((ks*4 + wr*2 + mf)*64 + lane) * 8;
                ah[mf]  = *(const bf16x8*)&Ah[idx];
                al2[mf] = *(const bf16x8*)&Al[idx];
            }
            #pragma unroll
            for (int nf = 0; nf < 2; ++nf) {
                const int idx = ((ks*4 + wc*2 + nf)*64 + lane) * 8;
                bh2[nf] = *(const bf16x8*)&Bh[idx];
                bl2[nf] = *(const bf16x8*)&Bl[idx];
            }
            #pragma unroll
            for (int mf = 0; mf < 2; ++mf)
                #pragma unroll
                for (int nf = 0; nf < 2; ++nf) {
                    acc[mf][nf] = __builtin_amdgcn_mfma_f32_32x32x16_bf16(ah[mf],  bh2[nf], acc[mf][nf], 0, 0, 0);
                    acc[mf][nf] = __builtin_amdgcn_mfma_f32_32x32x16_bf16(ah[mf],  bl2[nf], acc[mf][nf], 0, 0, 0);
                    acc[mf][nf] = __builtin_amdgcn_mfma_f32_32x32x16_bf16(al2[mf], bh2[nf], acc[mf][nf], 0, 0, 0);
                }
        }
        __syncthreads();
    }

    // ---- epilogue. C/D layout: col=lane&31, row=4*(lane>>5)+(r&3)+8*(r>>2)
    #pragma unroll
    for (int mf = 0; mf < 2; ++mf)
        #pragma unroll
        for (int nf = 0; nf < 2; ++nf) {
            const int gcol = blockIdx.x*128 + wc*64 + nf*32 + lr;
            const float bsv = bias[bn*128 + wc*64 + nf*32 + lr];
            #pragma unroll
            for (int r = 0; r < 16; ++r) {
                const int grow = bm*128 + wr*64 + mf*32 + kb*4 + (r & 3) + 8*(r >> 2);
                float o = (acc[mf][nf][r] + bsv) * scale;
                if (HAS_RES) o += res[(size_t)grow * ldc + gcol];
                if (LEAKY)   o = o > 0.f ? o : 0.2f * o;
                C[(size_t)grow * ldc + gcol] = o;
            }
        }
}

// ---------------------------------------------------------------- Attention
// grid (S/64, H+1, B); 256 threads. Flash-style over 8 key tiles of 64.
// q/k/v live in the fused qkv buffer [M][3072]: q @0, k @1024, v @2048.
__global__ __launch_bounds__(256)
void attn_kernel(const float* __restrict__ qkv, const float* __restrict__ mask,
                 const float* __restrict__ sattn, const float* __restrict__ sval,
                 float* __restrict__ comb)
{
    __shared__ float QsT[64][64];   // [d][i]
    __shared__ float KT [64][64];   // [d][j]  (reused as PsT[j][i])
    __shared__ float Vs [64][64];   // [j][d]
    const int tid = threadIdx.x;
    const int tx = tid & 15, ty = tid >> 4;
    const int qt = blockIdx.x, hh = blockIdx.y, b = blockIdx.z;
    const bool special = (hh == HH);

    const int li  = tid >> 2;          // 0..63
    const int ld0 = (tid & 3) * 16;    // 0,16,32,48

    if (!special) {
        const float* qbase = qkv + ((size_t)(b*SS + qt*64 + li)) * QKV_LD + hh*DHH;
        #pragma unroll
        for (int u = 0; u < 4; u++) {
            float4 t = *(const float4*)(qbase + ld0 + u*4);
            QsT[ld0+u*4+0][li] = t.x; QsT[ld0+u*4+1][li] = t.y;
            QsT[ld0+u*4+2][li] = t.z; QsT[ld0+u*4+3][li] = t.w;
        }
    }

    float m_i[4], l_i[4], oacc[4][4];
    #pragma unroll
    for (int r = 0; r < 4; r++) {
        m_i[r] = -FLT_MAX_;
        l_i[r] = special ? 1.f : 0.f;
        #pragma unroll
        for (int c = 0; c < 4; c++) oacc[r][c] = 0.f;
    }

    for (int kt = 0; kt < 8; ++kt) {
        __syncthreads();   // previous PV reads done
        if (!special) {
            const float* kbase = qkv + ((size_t)(b*SS + kt*64 + li)) * QKV_LD + HD + hh*DHH;
            #pragma unroll
            for (int u = 0; u < 4; u++) {
                float4 t = *(const float4*)(kbase + ld0 + u*4);
                KT[ld0+u*4+0][li] = t.x; KT[ld0+u*4+1][li] = t.y;
                KT[ld0+u*4+2][li] = t.z; KT[ld0+u*4+3][li] = t.w;
            }
        } else {
            const float* pbase = sattn + ((size_t)b*SS + qt*64 + li) * SS + kt*64;
            #pragma unroll
            for (int u = 0; u < 4; u++) {
                float4 t = *(const float4*)(pbase + ld0 + u*4);
                KT[ld0+u*4+0][li] = t.x; KT[ld0+u*4+1][li] = t.y;
                KT[ld0+u*4+2][li] = t.z; KT[ld0+u*4+3][li] = t.w;
            }
        }
        {
            const float* vbase = (hh == 0)
                ? (sval + ((size_t)b*SS + kt*64 + li) * DHH)
                : (qkv + ((size_t)(b*SS + kt*64 + li)) * QKV_LD + 2*HD + (hh-1)*DHH);
            #pragma unroll
            for (int u = 0; u < 4; u++) {
                float4 t = *(const float4*)(vbase + ld0 + u*4);
                *(float4*)&Vs[li][ld0 + u*4] = t;
            }
        }
        __syncthreads();

        if (!special) {
            float sc[4][4];
            #pragma unroll
            for (int r = 0; r < 4; r++)
                #pragma unroll
                for (int c = 0; c < 4; c++) sc[r][c] = 0.f;
            #pragma unroll 8
            for (int d = 0; d < 64; ++d) {
                float4 qa = *(const float4*)&QsT[d][ty*4];
                float4 kb = *(const float4*)&KT[d][tx*4];
                float av[4] = {qa.x, qa.y, qa.z, qa.w};
                float bv[4] = {kb.x, kb.y, kb.z, kb.w};
                #pragma unroll
                for (int r = 0; r < 4; r++)
                    #pragma unroll
                    for (int c = 0; c < 4; c++)
                        sc[r][c] = fmaf(av[r], bv[c], sc[r][c]);
            }
            #pragma unroll
            for (int c = 0; c < 4; c++) {
                const float mk = mask[b*SS + kt*64 + tx*4 + c];
                const float add = (1.0f - mk) * NEG_MIN;
                #pragma unroll
                for (int r = 0; r < 4; r++)
                    sc[r][c] = sc[r][c] * mk + add;
            }
            float p[4][4];
            #pragma unroll
            for (int r = 0; r < 4; r++) {
                float rm = fmaxf(fmaxf(sc[r][0], sc[r][1]), fmaxf(sc[r][2], sc[r][3]));
                #pragma unroll
                for (int off = 1; off < 16; off <<= 1)
                    rm = fmaxf(rm, __shfl_xor(rm, off));
                const float m_new = fmaxf(m_i[r], rm);
                const float corr  = __expf(m_i[r] - m_new);
                float rs = 0.f;
                #pragma unroll
                for (int c = 0; c < 4; c++) {
                    p[r][c] = __expf(sc[r][c] - m_new);
                    rs += p[r][c];
                }
                #pragma unroll
                for (int off = 1; off < 16; off <<= 1)
                    rs += __shfl_xor(rs, off);
                l_i[r] = l_i[r] * corr + rs;
                m_i[r] = m_new;
                #pragma unroll
                for (int c = 0; c < 4; c++) oacc[r][c] *= corr;
            }
            __syncthreads();   // done reading KT
            #pragma unroll
            for (int r = 0; r < 4; r++)
                #pragma unroll
                for (int c = 0; c < 4; c++)
                    KT[tx*4+c][ty*4+r] = p[r][c];   // PsT[j][i]
            __syncthreads();   // PsT ready
        }
        #pragma unroll 8
        for (int j = 0; j < 64; ++j) {
            float4 pa = *(const float4*)&KT[j][ty*4];
            float4 vb = *(const float4*)&Vs[j][tx*4];
            float av[4] = {pa.x, pa.y, pa.z, pa.w};
            float bv[4] = {vb.x, vb.y, vb.z, vb.w};
            #pragma unroll
            for (int r = 0; r < 4; r++)
                #pragma unroll
                for (int c = 0; c < 4; c++)
                    oacc[r][c] = fmaf(av[r], bv[c], oacc[r][c]);
        }
    }
    #pragma unroll
    for (int r = 0; r < 4; r++) {
        const size_t row = (size_t)(b*SS + qt*64 + ty*4 + r);
        const float invl = 1.0f / l_i[r];
        float4 o = { oacc[r][0]*invl, oacc[r][1]*invl, oacc[r][2]*invl, oacc[r][3]*invl };
        *(float4*)&comb[row * CD + hh*DHH + tx*4] = o;
    }
}

// ---------------------------------------------------------------- launch
extern "C" void kernel_launch(void* const* d_in, const int* in_sizes, int n_in,
                              void* d_out, int out_size, void* d_ws, size_t ws_size,
                              hipStream_t stream)
{
    const float* x     = (const float*)d_in[0];
    const float* mask  = (const float*)d_in[1];
    const float* sattn = (const float*)d_in[2];
    const float* sval  = (const float*)d_in[3];
    const float* Wq    = (const float*)d_in[4];
    const float* bq    = (const float*)d_in[5];
    const float* Wk    = (const float*)d_in[6];
    const float* bk    = (const float*)d_in[7];
    const float* Wv    = (const float*)d_in[8];
    const float* bv    = (const float*)d_in[9];
    const float* Wo    = (const float*)d_in[10];
    const float* bo    = (const float*)d_in[11];
    const float* ln1g  = (const float*)d_in[12];
    const float* ln1b  = (const float*)d_in[13];
    const float* W1    = (const float*)d_in[14];
    const float* b1    = (const float*)d_in[15];
    const float* W2    = (const float*)d_in[16];
    const float* b2    = (const float*)d_in[17];
    const float* ln2g  = (const float*)d_in[18];
    const float* ln2b  = (const float*)d_in[19];

    float* ws = (float*)d_ws;
    float* y    = ws;                    // 4096*1024
    float* qkv  = ws + 4194304;          // 4096*3072
    float* hb   = ws;                    // 4096*4096, aliases y+qkv (dead then)
    float* comb = ws + 16777216;         // 4096*1088
    float* x2   = ws + 21233664;         // 4096*1024
    float* y2   = ws + 25427968;         // 4096*1024

    const dim3 blk(256);

    ln_kernel<<<MM, blk, 0, stream>>>(x, ln1g, ln1b, y);

    gemm_mfma<true,false,false><<<dim3(24, 32), blk, 0, stream>>>(
        y, Wq, Wk, Wv, bq, bk, bv, nullptr, qkv, DD, DD, DD, QKV_LD);

    attn_kernel<<<dim3(SS/64, HH+1, BB), blk, 0, stream>>>(qkv, mask, sattn, sval, comb);

    gemm_mfma<false,true,false><<<dim3(8, 32), blk, 0, stream>>>(
        comb, Wo, nullptr, nullptr, bo, nullptr, nullptr, x, x2, CD, CD, DD, DD);

    ln_kernel<<<MM, blk, 0, stream>>>(x2, ln2g, ln2b, y2);

    gemm_mfma<false,false,true><<<dim3(32, 32), blk, 0, stream>>>(
        y2, W1, nullptr, nullptr, b1, nullptr, nullptr, nullptr, hb, DD, DD, FFF, FFF);

    gemm_mfma<false,true,false><<<dim3(8, 32), blk, 0, stream>>>(
        hb, W2, nullptr, nullptr, b2, nullptr, nullptr, x2, (float*)d_out, FFF, FFF, DD, DD);
}